// Round 6
// baseline (145.085 us; speedup 1.0000x reference)
//
#include <hip/hip_runtime.h>

// Problem constants (from reference setup_inputs): B=8, C=3, H=W=512
#define HW    262144        // 512*512
#define HW4   65536         // HW/4 float4 elements per channel
#define BC    24            // B*C channels
#define NB    256           // bins
#define NTOT  6291456       // B*C*H*W

#define GH    64            // hist blocks per channel (4 float4/thread)
#define GL    64            // loss blocks per channel (4 float4/thread)
#define TOTL  (BC * GL)     // 1536 loss blocks

// Workspace layout (bytes) — nothing needs pre-zeroing, no fences anywhere.
// finCnt is zeroed by a plain store in hist_kernel (kernel-boundary visible).
//   [0, 1572864)            hsPart : int[24][GH][256]
//   [1572864, 3145728)      hrPart : int[24][GH][256]
//   [3145728, 3170304)      lut    : float[24][256]
//   [3170304, 3176448)      lsum   : float[TOTL]
//   [3176448, 3176452)      finCnt : unsigned
//   [3176464, 9467920)      qb     : uchar[24][HW]      quantized ref bin
//   [9467920, 10254352)     mb     : ushort[24][16384]   16 mask bits/thread-slot
#define WS_HSP_OFF   0
#define WS_HRP_OFF   1572864
#define WS_LUT_OFF   3145728
#define WS_LSUM_OFF  3170304
#define WS_CNT_OFF   3176448
#define WS_QB_OFF    3176464
#define WS_MB_OFF    9467920

__device__ __forceinline__ int quantize(float x, float m) {
    // jnp.clip(jnp.round((x+1)*0.5*255 * m), 0, 255)
    float v = (x + 1.0f) * 0.5f * 255.0f * m;
    float r = rintf(v);
    r = fminf(fmaxf(r, 0.0f), 255.0f);
    return (int)r;
}

// Inclusive scan over 256 ints via wave shuffles: 6 shfl_up + 2 barriers.
// Integer adds — bitwise-identical result to the LDS-ladder version.
__device__ __forceinline__ int incl_scan256(int v, int t, int* buf4, int* tot) {
    const int lane = t & 63;
    const int wave = t >> 6;
#pragma unroll
    for (int off = 1; off < 64; off <<= 1) {
        int y = __shfl_up(v, off, 64);
        if (lane >= off) v += y;
    }
    __syncthreads();              // protect buf4 reuse across calls
    if (lane == 63) buf4[wave] = v;
    __syncthreads();
    int add = 0;
#pragma unroll
    for (int w = 0; w < 4; ++w) if (w < wave) add += buf4[w];
    *tot = buf4[0] + buf4[1] + buf4[2] + buf4[3];
    return v + add;
}

// ---------------- Stage 1: per-channel partial histograms + qb/mb store ----
// grid dim3(GH, 24), block 256. All 16 float4 loads issued before use.
// Plain coalesced partial stores — NO device atomics, NO threadfence.
// Emits per-pixel quantized bin (uchar) + per-thread-slot 16 mask bits so
// stage 3 never re-reads ref/ms. (6.75 MB sidecar vs 12 MB ushort version.)
__global__ void __launch_bounds__(256)
hist_kernel(const float4* __restrict__ ref4,
            const float4* __restrict__ tar4,
            const float4* __restrict__ ms4,
            const float4* __restrict__ mt4,
            int* __restrict__ hsPart, int* __restrict__ hrPart,
            uchar4* __restrict__ qb, unsigned short* __restrict__ mb,
            unsigned* __restrict__ finCnt) {
    __shared__ int wh[4 * 2 * NB];        // [wave][s/r][bin]
    const int t = threadIdx.x;
    const int wave = t >> 6;
    const int lane = t & 63;

    // zero the stage-3 finalize counter (plain store; kernel-boundary visible)
    if (blockIdx.x == 0 && blockIdx.y == 0 && t == 0) *finCnt = 0u;

#pragma unroll
    for (int j = 0; j < 8; ++j) wh[t + j * 256] = 0;
    __syncthreads();

    const int c = blockIdx.y;
    const int b = c / 3;
    const float4* refc = ref4 + (size_t)c * HW4;
    const float4* tarc = tar4 + (size_t)c * HW4;
    const float4* msb  = ms4 + (size_t)b * HW4;
    const float4* mtb  = mt4 + (size_t)b * HW4;
    uchar4* qbc = qb + (size_t)c * HW4;
    unsigned short* mbc = mb + (size_t)c * (GH * 256);

    const int base = blockIdx.x * 256 + t;   // stride GH*256 = 16384

    // ---- load phase: 16 independent float4 loads in flight ----
    float4 R[4], T[4], M[4], MT[4];
#pragma unroll
    for (int j = 0; j < 4; ++j) R[j]  = refc[base + j * 16384];
#pragma unroll
    for (int j = 0; j < 4; ++j) M[j]  = msb[base + j * 16384];
#pragma unroll
    for (int j = 0; j < 4; ++j) T[j]  = tarc[base + j * 16384];
#pragma unroll
    for (int j = 0; j < 4; ++j) MT[j] = mtb[base + j * 16384];

    // ---- process phase ----
    int* whS = &wh[wave * 512];
    int* whR = &wh[wave * 512 + 256];
    int n0s = 0, n0r = 0;
    unsigned mbits = 0u;                  // 16 mask-src bits (j*4+k)
#pragma unroll
    for (int j = 0; j < 4; ++j) {
        const float rv[4]  = {R[j].x, R[j].y, R[j].z, R[j].w};
        const float mv[4]  = {M[j].x, M[j].y, M[j].z, M[j].w};
        const float tvv[4] = {T[j].x, T[j].y, T[j].z, T[j].w};
        const float mtv[4] = {MT[j].x, MT[j].y, MT[j].z, MT[j].w};
        unsigned q8[4];
#pragma unroll
        for (int k = 0; k < 4; ++k) {
            const int qs = quantize(rv[k], mv[k]);   // 0 when mask==0
            q8[k] = (unsigned)qs;
            if (mv[k] != 0.0f) { atomicAdd(&whS[qs], 1); mbits |= 1u << (j * 4 + k); }
            else n0s++;
            if (mtv[k] != 0.0f) atomicAdd(&whR[quantize(tvv[k], mtv[k])], 1);
            else n0r++;
        }
        uchar4 qq;
        qq.x = (unsigned char)q8[0];
        qq.y = (unsigned char)q8[1];
        qq.z = (unsigned char)q8[2];
        qq.w = (unsigned char)q8[3];
        qbc[base + j * 16384] = qq;
    }
    mbc[base] = (unsigned short)mbits;

    // fold register bin-0 counts: wave-reduce, one LDS add per wave
#pragma unroll
    for (int off = 32; off > 0; off >>= 1) {
        n0s += __shfl_down(n0s, off);
        n0r += __shfl_down(n0r, off);
    }
    if (lane == 0) {
        if (n0s) atomicAdd(&whS[0], n0s);
        if (n0r) atomicAdd(&whR[0], n0r);
    }
    __syncthreads();

    // merge 4 wave-hists -> per-block partial, plain coalesced store
    const int s = wh[t] + wh[512 + t] + wh[1024 + t] + wh[1536 + t];
    const int r = wh[256 + t] + wh[768 + t] + wh[1280 + t] + wh[1792 + t];
    hsPart[(c * GH + blockIdx.x) * NB + t] = s;
    hrPart[(c * GH + blockIdx.x) * NB + t] = r;
}

// ---------------- Stage 2: per-channel matching LUT ----------------
// 24 blocks; thread t owns bin t. Sums the GH partials (L2-hot, 3 MB total),
// then shuffle-scan + interp. Identical math to the verified lut_kernel.
__global__ void __launch_bounds__(256)
lut_kernel(const int* __restrict__ hsPart,
           const int* __restrict__ hrPart,
           float* __restrict__ lut) {
    const int c = blockIdx.x;
    const int t = threadIdx.x;

    __shared__ int   buf4[4];
    __shared__ float xp[NB];
    __shared__ float fp[NB];
    __shared__ int firstS, firstR, nOccS, nOccR;

    int cs = 0, cr = 0;
#pragma unroll 8
    for (int g = 0; g < GH; ++g) {
        cs += hsPart[(c * GH + g) * NB + t];
        cr += hrPart[(c * GH + g) * NB + t];
    }

    if (t == 0) { firstS = NB; firstR = NB; nOccS = 0; nOccR = 0; }
    __syncthreads();
    if (cs > 0) { atomicMin(&firstS, t); atomicAdd(&nOccS, 1); }
    if (cr > 0) { atomicMin(&firstR, t); atomicAdd(&nOccR, 1); }
    __syncthreads();

    const int csz = (t == firstS) ? 0 : cs;
    const int crz = (t == firstR) ? 0 : cr;

    int totS, totR, dummy;
    const int cumS = incl_scan256(csz, t, buf4, &totS);
    const int cumR = incl_scan256(crz, t, buf4, &totR);
    const int occ2 = (cr > 0 && t != firstR) ? 1 : 0;
    const int rank = incl_scan256(occ2, t, buf4, &dummy) - occ2;  // exclusive

    const float x  = (float)cumS / fmaxf((float)totS, 1.0f);
    const float rq = (float)cumR / fmaxf((float)totR, 1.0f);

    xp[t] = 2.0f;
    fp[t] = 0.0f;
    __syncthreads();
    if (occ2) { xp[rank] = rq; fp[rank] = (float)t; }
    __syncthreads();

    // jnp.interp semantics: searchsorted-right, i clipped to [1,255]
    int lo = 0, hi = NB;
    while (lo < hi) {
        int mid = (lo + hi) >> 1;
        if (xp[mid] > x) hi = mid; else lo = mid + 1;
    }
    int i2 = lo;
    i2 = (i2 < 1) ? 1 : ((i2 > NB - 1) ? NB - 1 : i2);
    float dxv = xp[i2] - xp[i2 - 1];
    float f;
    if (dxv == 0.0f) f = fp[i2];
    else f = fp[i2 - 1] + (x - xp[i2 - 1]) / dxv * (fp[i2] - fp[i2 - 1]);
    if (x < xp[0]) f = fp[0];

    float l = truncf(f);
    if (t == firstS) l = 0.0f;
    if (!((nOccS > 1) && (nOccR > 1))) l = 0.0f;

    lut[c * NB + t] = l;
}

// ---------------- Stage 3: apply LUT + masked L1 + last-block finalize -----
// grid dim3(GL, 24), block 256. q from qb, mask bits from mb — only
// inp+qb+mb from HBM (~30.75 MB). Finalize fused via last-block counter:
// lsum published with atomicExch (coherent point), exchange completion
// enforced by consuming the returned value before the counter increment —
// no threadfence, no L2 writeback. Reduce order identical to the old
// finalize_kernel -> bitwise-same output.
__global__ void __launch_bounds__(256)
loss_kernel(const float4* __restrict__ inp4,
            const uchar4* __restrict__ qb,
            const unsigned short* __restrict__ mb,
            const float* __restrict__ lut,
            float* __restrict__ lsum,
            unsigned* __restrict__ finCnt,
            float* __restrict__ out) {
    __shared__ float llut[NB];
    __shared__ float wsum[4];
    __shared__ int isLast;
    const int t = threadIdx.x;
    const int c = blockIdx.y;
    const int g = blockIdx.x;
    const int lane = t & 63;
    const int wave = t >> 6;

    const float4* inpc = inp4 + (size_t)c * HW4;
    const uchar4* qbc  = qb + (size_t)c * HW4;
    const unsigned short* mbc = mb + (size_t)c * (GL * 256);
    const int base = g * 256 + t;            // stride GL*256 = 16384

    // issue bulk loads first; llut fill overlaps their latency
    float4 X[4];
    uchar4 Q[4];
#pragma unroll
    for (int j = 0; j < 4; ++j) X[j] = inpc[base + j * 16384];
#pragma unroll
    for (int j = 0; j < 4; ++j) Q[j] = qbc[base + j * 16384];
    const unsigned mbits = (unsigned)mbc[base];

    llut[t] = lut[c * NB + t];
    __syncthreads();

    float s = 0.0f;
#pragma unroll
    for (int j = 0; j < 4; ++j) {
        const float xv[4] = {X[j].x, X[j].y, X[j].z, X[j].w};
        const unsigned qv[4] = {Q[j].x, Q[j].y, Q[j].z, Q[j].w};
#pragma unroll
        for (int k = 0; k < 4; ++k) {
            const float mf = (float)((mbits >> (j * 4 + k)) & 1u);
            const float im = (xv[k] + 1.0f) * 127.5f;
            s += mf * fabsf(im - llut[qv[k]]);
        }
    }

#pragma unroll
    for (int off = 32; off > 0; off >>= 1) s += __shfl_down(s, off);
    if (lane == 0) wsum[wave] = s;
    __syncthreads();
    if (t == 0) {
        const float blockSum = wsum[0] + wsum[1] + wsum[2] + wsum[3];
        // publish at the coherent point; returned old value forces vmcnt wait
        float old = atomicExch(&lsum[c * GL + g], blockSum);
        asm volatile("" :: "v"(old) : "memory");   // order counter after exch
        unsigned prev = atomicAdd(finCnt, 1u);
        isLast = (prev == (unsigned)(TOTL - 1)) ? 1 : 0;
    }
    __syncthreads();

    // ---- last block: deterministic final reduce (same order as before) ----
    if (isLast) {
        float ss = 0.0f;
#pragma unroll 2
        for (int i = t; i < TOTL; i += 256)
            ss += atomicAdd(&lsum[i], 0.0f);   // coherent read (cross-XCD safe)
#pragma unroll
        for (int off = 32; off > 0; off >>= 1) ss += __shfl_down(ss, off);
        if (lane == 0) wsum[wave] = ss;
        __syncthreads();
        if (t == 0)
            out[0] = (wsum[0] + wsum[1] + wsum[2] + wsum[3]) / (float)NTOT;
    }
}

extern "C" void kernel_launch(void* const* d_in, const int* in_sizes, int n_in,
                              void* d_out, int out_size, void* d_ws, size_t ws_size,
                              hipStream_t stream) {
    const float* inp  = (const float*)d_in[0];
    const float* tar  = (const float*)d_in[1];
    const float* ref  = (const float*)d_in[2];
    const float* msrc = (const float*)d_in[3];
    const float* mtar = (const float*)d_in[4];

    char* ws = (char*)d_ws;
    int*            hsPart = (int*)(ws + WS_HSP_OFF);
    int*            hrPart = (int*)(ws + WS_HRP_OFF);
    float*          lut    = (float*)(ws + WS_LUT_OFF);
    float*          lsum   = (float*)(ws + WS_LSUM_OFF);
    unsigned*       finCnt = (unsigned*)(ws + WS_CNT_OFF);
    uchar4*         qb     = (uchar4*)(ws + WS_QB_OFF);
    unsigned short* mb     = (unsigned short*)(ws + WS_MB_OFF);

    hist_kernel<<<dim3(GH, BC), 256, 0, stream>>>(
        (const float4*)ref, (const float4*)tar,
        (const float4*)msrc, (const float4*)mtar,
        hsPart, hrPart, qb, mb, finCnt);

    lut_kernel<<<BC, 256, 0, stream>>>(hsPart, hrPart, lut);

    loss_kernel<<<dim3(GL, BC), 256, 0, stream>>>(
        (const float4*)inp, qb, mb, lut, lsum, finCnt, (float*)d_out);
}

// Round 7
// 128.822 us; speedup vs baseline: 1.1262x; 1.1262x over previous
//
#include <hip/hip_runtime.h>

// Problem constants (from reference setup_inputs): B=8, C=3, H=W=512
#define HW    262144        // 512*512
#define HW4   65536         // HW/4 float4 elements per channel
#define BC    24            // B*C channels
#define NB    256           // bins
#define NTOT  6291456       // B*C*H*W

#define GH    64            // hist blocks per channel (4 float4/thread)
#define GL    64            // loss blocks per channel (4 float4/thread)
#define TOTL  (BC * GL)     // 1536 loss blocks

// Workspace layout (bytes) — nothing needs pre-zeroing, no device atomics,
// no fences, no counters. All producer->consumer visibility is via kernel
// launch boundaries (proven free; every coordination primitive measured
// worse: grid.sync ~100us/barrier, per-block threadfence ~200us/grid,
// single-line per-block atomics ~15us/1536 blocks).
//   [0, 1572864)            hsPart : int[24][GH][256]
//   [1572864, 3145728)      hrPart : int[24][GH][256]
//   [3145728, 3170304)      lut    : float[24][256]
//   [3170304, 3176448)      lsum   : float[TOTL]
//   [3176448, 9467904)      qb     : uchar[24][HW]      quantized ref bin
//   [9467904, 10254336)     mb     : ushort[24][16384]  16 mask bits/thread-slot
#define WS_HSP_OFF   0
#define WS_HRP_OFF   1572864
#define WS_LUT_OFF   3145728
#define WS_LSUM_OFF  3170304
#define WS_QB_OFF    3176448
#define WS_MB_OFF    9467904

__device__ __forceinline__ int quantize(float x, float m) {
    // jnp.clip(jnp.round((x+1)*0.5*255 * m), 0, 255)
    float v = (x + 1.0f) * 0.5f * 255.0f * m;
    float r = rintf(v);
    r = fminf(fmaxf(r, 0.0f), 255.0f);
    return (int)r;
}

// Inclusive scan over 256 ints via wave shuffles: 6 shfl_up + 2 barriers.
// Integer adds — bitwise-identical result to the LDS-ladder version.
__device__ __forceinline__ int incl_scan256(int v, int t, int* buf4, int* tot) {
    const int lane = t & 63;
    const int wave = t >> 6;
#pragma unroll
    for (int off = 1; off < 64; off <<= 1) {
        int y = __shfl_up(v, off, 64);
        if (lane >= off) v += y;
    }
    __syncthreads();              // protect buf4 reuse across calls
    if (lane == 63) buf4[wave] = v;
    __syncthreads();
    int add = 0;
#pragma unroll
    for (int w = 0; w < 4; ++w) if (w < wave) add += buf4[w];
    *tot = buf4[0] + buf4[1] + buf4[2] + buf4[3];
    return v + add;
}

// ---------------- Stage 1: per-channel partial histograms + qb/mb store ----
// grid dim3(GH, 24), block 256. All 16 float4 loads issued before use.
// Plain coalesced partial stores — NO device atomics, NO threadfence.
// Emits per-pixel quantized bin (uchar) + 16 mask bits per thread-slot so
// stage 3 never re-reads ref/ms (7.5 MB sidecar vs 12 MB ushort version).
__global__ void __launch_bounds__(256)
hist_kernel(const float4* __restrict__ ref4,
            const float4* __restrict__ tar4,
            const float4* __restrict__ ms4,
            const float4* __restrict__ mt4,
            int* __restrict__ hsPart, int* __restrict__ hrPart,
            uchar4* __restrict__ qb, unsigned short* __restrict__ mb) {
    __shared__ int wh[4 * 2 * NB];        // [wave][s/r][bin]
    const int t = threadIdx.x;
    const int wave = t >> 6;
    const int lane = t & 63;
#pragma unroll
    for (int j = 0; j < 8; ++j) wh[t + j * 256] = 0;
    __syncthreads();

    const int c = blockIdx.y;
    const int b = c / 3;
    const float4* refc = ref4 + (size_t)c * HW4;
    const float4* tarc = tar4 + (size_t)c * HW4;
    const float4* msb  = ms4 + (size_t)b * HW4;
    const float4* mtb  = mt4 + (size_t)b * HW4;
    uchar4* qbc = qb + (size_t)c * HW4;
    unsigned short* mbc = mb + (size_t)c * (GH * 256);

    const int base = blockIdx.x * 256 + t;   // stride GH*256 = 16384

    // ---- load phase: 16 independent float4 loads in flight ----
    float4 R[4], T[4], M[4], MT[4];
#pragma unroll
    for (int j = 0; j < 4; ++j) R[j]  = refc[base + j * 16384];
#pragma unroll
    for (int j = 0; j < 4; ++j) M[j]  = msb[base + j * 16384];
#pragma unroll
    for (int j = 0; j < 4; ++j) T[j]  = tarc[base + j * 16384];
#pragma unroll
    for (int j = 0; j < 4; ++j) MT[j] = mtb[base + j * 16384];

    // ---- process phase ----
    int* whS = &wh[wave * 512];
    int* whR = &wh[wave * 512 + 256];
    int n0s = 0, n0r = 0;
    unsigned mbits = 0u;                  // 16 mask-src bits (j*4+k)
#pragma unroll
    for (int j = 0; j < 4; ++j) {
        const float rv[4]  = {R[j].x, R[j].y, R[j].z, R[j].w};
        const float mv[4]  = {M[j].x, M[j].y, M[j].z, M[j].w};
        const float tvv[4] = {T[j].x, T[j].y, T[j].z, T[j].w};
        const float mtv[4] = {MT[j].x, MT[j].y, MT[j].z, MT[j].w};
        unsigned q8[4];
#pragma unroll
        for (int k = 0; k < 4; ++k) {
            const int qs = quantize(rv[k], mv[k]);   // 0 when mask==0
            q8[k] = (unsigned)qs;
            if (mv[k] != 0.0f) { atomicAdd(&whS[qs], 1); mbits |= 1u << (j * 4 + k); }
            else n0s++;
            if (mtv[k] != 0.0f) atomicAdd(&whR[quantize(tvv[k], mtv[k])], 1);
            else n0r++;
        }
        uchar4 qq;
        qq.x = (unsigned char)q8[0];
        qq.y = (unsigned char)q8[1];
        qq.z = (unsigned char)q8[2];
        qq.w = (unsigned char)q8[3];
        qbc[base + j * 16384] = qq;
    }
    mbc[base] = (unsigned short)mbits;

    // fold register bin-0 counts: wave-reduce, one LDS add per wave
#pragma unroll
    for (int off = 32; off > 0; off >>= 1) {
        n0s += __shfl_down(n0s, off);
        n0r += __shfl_down(n0r, off);
    }
    if (lane == 0) {
        if (n0s) atomicAdd(&whS[0], n0s);
        if (n0r) atomicAdd(&whR[0], n0r);
    }
    __syncthreads();

    // merge 4 wave-hists -> per-block partial, plain coalesced store
    const int s = wh[t] + wh[512 + t] + wh[1024 + t] + wh[1536 + t];
    const int r = wh[256 + t] + wh[768 + t] + wh[1280 + t] + wh[1792 + t];
    hsPart[(c * GH + blockIdx.x) * NB + t] = s;
    hrPart[(c * GH + blockIdx.x) * NB + t] = r;
}

// ---------------- Stage 2: per-channel matching LUT ----------------
// 24 blocks; thread t owns bin t. Sums the GH partials (L2-hot, 3 MB total),
// then shuffle-scan + interp. Identical math to the verified lut_kernel.
__global__ void __launch_bounds__(256)
lut_kernel(const int* __restrict__ hsPart,
           const int* __restrict__ hrPart,
           float* __restrict__ lut) {
    const int c = blockIdx.x;
    const int t = threadIdx.x;

    __shared__ int   buf4[4];
    __shared__ float xp[NB];
    __shared__ float fp[NB];
    __shared__ int firstS, firstR, nOccS, nOccR;

    int cs = 0, cr = 0;
#pragma unroll 8
    for (int g = 0; g < GH; ++g) {
        cs += hsPart[(c * GH + g) * NB + t];
        cr += hrPart[(c * GH + g) * NB + t];
    }

    if (t == 0) { firstS = NB; firstR = NB; nOccS = 0; nOccR = 0; }
    __syncthreads();
    if (cs > 0) { atomicMin(&firstS, t); atomicAdd(&nOccS, 1); }
    if (cr > 0) { atomicMin(&firstR, t); atomicAdd(&nOccR, 1); }
    __syncthreads();

    const int csz = (t == firstS) ? 0 : cs;
    const int crz = (t == firstR) ? 0 : cr;

    int totS, totR, dummy;
    const int cumS = incl_scan256(csz, t, buf4, &totS);
    const int cumR = incl_scan256(crz, t, buf4, &totR);
    const int occ2 = (cr > 0 && t != firstR) ? 1 : 0;
    const int rank = incl_scan256(occ2, t, buf4, &dummy) - occ2;  // exclusive

    const float x  = (float)cumS / fmaxf((float)totS, 1.0f);
    const float rq = (float)cumR / fmaxf((float)totR, 1.0f);

    xp[t] = 2.0f;
    fp[t] = 0.0f;
    __syncthreads();
    if (occ2) { xp[rank] = rq; fp[rank] = (float)t; }
    __syncthreads();

    // jnp.interp semantics: searchsorted-right, i clipped to [1,255]
    int lo = 0, hi = NB;
    while (lo < hi) {
        int mid = (lo + hi) >> 1;
        if (xp[mid] > x) hi = mid; else lo = mid + 1;
    }
    int i2 = lo;
    i2 = (i2 < 1) ? 1 : ((i2 > NB - 1) ? NB - 1 : i2);
    float dxv = xp[i2] - xp[i2 - 1];
    float f;
    if (dxv == 0.0f) f = fp[i2];
    else f = fp[i2 - 1] + (x - xp[i2 - 1]) / dxv * (fp[i2] - fp[i2 - 1]);
    if (x < xp[0]) f = fp[0];

    float l = truncf(f);
    if (t == firstS) l = 0.0f;
    if (!((nOccS > 1) && (nOccR > 1))) l = 0.0f;

    lut[c * NB + t] = l;
}

// ---------------- Stage 3: apply LUT + masked L1, per-block partial --------
// grid dim3(GL, 24), block 256. q from qb, mask bits from mb — only
// inp+qb+mb from HBM/L3 (~31.5 MB). Plain partial store; no atomics.
__global__ void __launch_bounds__(256)
loss_kernel(const float4* __restrict__ inp4,
            const uchar4* __restrict__ qb,
            const unsigned short* __restrict__ mb,
            const float* __restrict__ lut,
            float* __restrict__ lsum) {
    __shared__ float llut[NB];
    __shared__ float wsum[4];
    const int t = threadIdx.x;
    const int c = blockIdx.y;
    const int g = blockIdx.x;
    const int lane = t & 63;
    const int wave = t >> 6;

    const float4* inpc = inp4 + (size_t)c * HW4;
    const uchar4* qbc  = qb + (size_t)c * HW4;
    const unsigned short* mbc = mb + (size_t)c * (GL * 256);
    const int base = g * 256 + t;            // stride GL*256 = 16384

    // issue bulk loads first; llut fill overlaps their latency
    float4 X[4];
    uchar4 Q[4];
#pragma unroll
    for (int j = 0; j < 4; ++j) X[j] = inpc[base + j * 16384];
#pragma unroll
    for (int j = 0; j < 4; ++j) Q[j] = qbc[base + j * 16384];
    const unsigned mbits = (unsigned)mbc[base];

    llut[t] = lut[c * NB + t];
    __syncthreads();

    float s = 0.0f;
#pragma unroll
    for (int j = 0; j < 4; ++j) {
        const float xv[4] = {X[j].x, X[j].y, X[j].z, X[j].w};
        const unsigned qv[4] = {Q[j].x, Q[j].y, Q[j].z, Q[j].w};
#pragma unroll
        for (int k = 0; k < 4; ++k) {
            const float mf = (float)((mbits >> (j * 4 + k)) & 1u);
            const float im = (xv[k] + 1.0f) * 127.5f;
            s += mf * fabsf(im - llut[qv[k]]);
        }
    }

#pragma unroll
    for (int off = 32; off > 0; off >>= 1) s += __shfl_down(s, off);
    if (lane == 0) wsum[wave] = s;
    __syncthreads();
    if (t == 0)
        lsum[c * GL + g] = wsum[0] + wsum[1] + wsum[2] + wsum[3];
}

// ---------------- Stage 4: final reduction ----------------
__global__ void __launch_bounds__(256)
finalize_kernel(const float* __restrict__ lsum, float* __restrict__ out) {
    const int t = threadIdx.x;
    float s = 0.0f;
#pragma unroll
    for (int i = t; i < TOTL; i += 256) s += lsum[i];
#pragma unroll
    for (int off = 32; off > 0; off >>= 1) s += __shfl_down(s, off);
    __shared__ float wsum[4];
    const int lane = t & 63;
    const int wave = t >> 6;
    if (lane == 0) wsum[wave] = s;
    __syncthreads();
    if (t == 0)
        out[0] = (wsum[0] + wsum[1] + wsum[2] + wsum[3]) / (float)NTOT;
}

extern "C" void kernel_launch(void* const* d_in, const int* in_sizes, int n_in,
                              void* d_out, int out_size, void* d_ws, size_t ws_size,
                              hipStream_t stream) {
    const float* inp  = (const float*)d_in[0];
    const float* tar  = (const float*)d_in[1];
    const float* ref  = (const float*)d_in[2];
    const float* msrc = (const float*)d_in[3];
    const float* mtar = (const float*)d_in[4];

    char* ws = (char*)d_ws;
    int*            hsPart = (int*)(ws + WS_HSP_OFF);
    int*            hrPart = (int*)(ws + WS_HRP_OFF);
    float*          lut    = (float*)(ws + WS_LUT_OFF);
    float*          lsum   = (float*)(ws + WS_LSUM_OFF);
    uchar4*         qb     = (uchar4*)(ws + WS_QB_OFF);
    unsigned short* mb     = (unsigned short*)(ws + WS_MB_OFF);

    hist_kernel<<<dim3(GH, BC), 256, 0, stream>>>(
        (const float4*)ref, (const float4*)tar,
        (const float4*)msrc, (const float4*)mtar,
        hsPart, hrPart, qb, mb);

    lut_kernel<<<BC, 256, 0, stream>>>(hsPart, hrPart, lut);

    loss_kernel<<<dim3(GL, BC), 256, 0, stream>>>(
        (const float4*)inp, qb, mb, lut, lsum);

    finalize_kernel<<<1, 256, 0, stream>>>(lsum, (float*)d_out);
}